// Round 5
// baseline (610.008 us; speedup 1.0000x reference)
//
#include <hip/hip_runtime.h>
#include <hip/hip_fp16.h>

#define HH 352
#define WW 1216
#define HW (HH*WW)
#define NPIX (2*HW)      // 856064
#define NITER 18
#define PACK_BYTES ((size_t)NPIX * 64)

__device__ __forceinline__ float2 ld2(const float* p) {
    float2 v;
    __builtin_memcpy(&v, p, 8);   // 4B-aligned ok on gfx950 (unaligned mode)
    return v;
}

// ---------------------------------------------------------------------------
// Guarded per-pixel conv accumulate (boundary slow path).
// ---------------------------------------------------------------------------
__device__ __forceinline__ void conv_px_guarded(const float* __restrict__ gb,
                                                const float* __restrict__ cw,
                                                int y, int x, float acc[27]) {
    for (int ci = 0; ci < 9; ++ci) {
        const float* cp = gb + (size_t)ci * HW;
        float v[9];
#pragma unroll
        for (int t = 0; t < 9; ++t) {
            int yy = y + t / 3 - 1;
            int xx = x + t % 3 - 1;
            v[t] = ((unsigned)yy < HH && (unsigned)xx < WW)
                       ? cp[(size_t)yy * WW + xx] : 0.f;
        }
#pragma unroll
        for (int t = 0; t < 9; ++t)
#pragma unroll
            for (int co = 0; co < 27; ++co)
                acc[co] = fmaf(v[t], cw[co * 81 + ci * 9 + t], acc[co]);
    }
}

// ---------------------------------------------------------------------------
// Per-pixel epilogue: fp16 quantize offsets, softmax+fp16 aff, write f32
// outputs + packed record.
// ---------------------------------------------------------------------------
__device__ __forceinline__ void conv_epilogue(const float acc[27],
                                              int b, int r, int p,
                                              const float* __restrict__ confidence,
                                              const float* __restrict__ feat_fix,
                                              float* __restrict__ out_off,
                                              float* __restrict__ out_aff,
                                              uint4* __restrict__ packed) {
    __half h[28];
#pragma unroll
    for (int c = 0; c < 18; ++c) h[c] = __float2half(acc[c]);

    float m = acc[18];
#pragma unroll
    for (int c = 19; c < 27; ++c) m = fmaxf(m, acc[c]);
    float e[9], s = 0.f;
#pragma unroll
    for (int k = 0; k < 9; ++k) { e[k] = expf(acc[18 + k] - m); s += e[k]; }
    float inv = 1.f / s;
#pragma unroll
    for (int k = 0; k < 9; ++k) h[18 + k] = __float2half(e[k] * inv);
    h[27] = __float2half(0.f);

#pragma unroll
    for (int c = 0; c < 18; ++c)
        out_off[(size_t)b * 18 * HW + (size_t)c * HW + r] = __half2float(h[c]);
#pragma unroll
    for (int k = 0; k < 9; ++k)
        out_aff[(size_t)b * 9 * HW + (size_t)k * HW + r] = __half2float(h[18 + k]);

    if (packed) {
        float cf = confidence[p];
        float ff = feat_fix[p];
        float sg = (ff > 0.f) ? 1.f : ((ff < 0.f) ? -1.f : 0.f);
        float conf = sg / (1.f + expf(-cf));

        unsigned uu[16];
#pragma unroll
        for (int i = 0; i < 14; ++i)
            uu[i] = (unsigned)__half_as_ushort(h[2 * i]) |
                    ((unsigned)__half_as_ushort(h[2 * i + 1]) << 16);
        uu[14] = __float_as_uint(1.f - conf);   // cm1
        uu[15] = __float_as_uint(conf * ff);    // cff

        uint4* dst = packed + (size_t)p * 4;
        dst[0] = make_uint4(uu[0], uu[1], uu[2], uu[3]);
        dst[1] = make_uint4(uu[4], uu[5], uu[6], uu[7]);
        dst[2] = make_uint4(uu[8], uu[9], uu[10], uu[11]);
        dst[3] = make_uint4(uu[12], uu[13], uu[14], uu[15]);
    }
}

// ---------------------------------------------------------------------------
// Kernel A: 3x3 conv (9->27ch, pad 1), 2 pixels/thread, float2 packed FMA.
// ---------------------------------------------------------------------------
__global__ __launch_bounds__(256) void conv_pack_kernel(
    const float* __restrict__ g,          // [B,9,H,W]
    const float* __restrict__ cw,         // [27,9,3,3]
    const float* __restrict__ cb,         // [27]
    const float* __restrict__ confidence, // [B,1,H,W]
    const float* __restrict__ feat_fix,   // [B,1,H,W]
    float* __restrict__ out_off,          // [B,18,H,W]
    float* __restrict__ out_aff,          // [B,9,H,W]
    uint4* __restrict__ packed)           // [NPIX][4] or nullptr
{
    int p2 = blockIdx.x * 256 + threadIdx.x;
    if (p2 >= NPIX / 2) return;
    int p = 2 * p2;                 // first pixel of the pair (x even)
    int b = p / HW;
    int r = p - b * HW;
    int y = r / WW;
    int x = r - y * WW;

    const float* gb = g + (size_t)b * 9 * HW;
    bool interior = (y >= 1) & (y <= HH - 2) & (x >= 2) & (x <= WW - 4);

    float2 acc2[27];
#pragma unroll
    for (int co = 0; co < 27; ++co) { float cbv = cb[co]; acc2[co] = make_float2(cbv, cbv); }

    if (interior) {
        const float* c0 = gb + (size_t)(y - 1) * WW + x;
        for (int ci = 0; ci < 9; ++ci) {
            const float* cp = c0 + (size_t)ci * HW;
            // rows y-1..y+1, cols x-1..x+2 : scalar | float2 | scalar
            float  a0 = cp[-1];          float2 m0 = ld2(cp);          float b0 = cp[2];
            float  a1 = cp[WW - 1];      float2 m1 = ld2(cp + WW);     float b1 = cp[WW + 2];
            float  a2 = cp[2*WW - 1];    float2 m2 = ld2(cp + 2*WW);   float b2 = cp[2*WW + 2];
            float2 v2[9];
            v2[0] = make_float2(a0, m0.x); v2[1] = make_float2(m0.x, m0.y); v2[2] = make_float2(m0.y, b0);
            v2[3] = make_float2(a1, m1.x); v2[4] = make_float2(m1.x, m1.y); v2[5] = make_float2(m1.y, b1);
            v2[6] = make_float2(a2, m2.x); v2[7] = make_float2(m2.x, m2.y); v2[8] = make_float2(m2.y, b2);
#pragma unroll
            for (int t = 0; t < 9; ++t)
#pragma unroll
                for (int co = 0; co < 27; ++co) {
                    float wv = cw[co * 81 + ci * 9 + t];
                    acc2[co].x = fmaf(v2[t].x, wv, acc2[co].x);
                    acc2[co].y = fmaf(v2[t].y, wv, acc2[co].y);
                }
        }
    } else {
        float a0[27], a1[27];
#pragma unroll
        for (int co = 0; co < 27; ++co) { a0[co] = acc2[co].x; a1[co] = acc2[co].y; }
        conv_px_guarded(gb, cw, y, x, a0);
        conv_px_guarded(gb, cw, y, x + 1, a1);
#pragma unroll
        for (int co = 0; co < 27; ++co) acc2[co] = make_float2(a0[co], a1[co]);
    }

    float accA[27], accB[27];
#pragma unroll
    for (int co = 0; co < 27; ++co) { accA[co] = acc2[co].x; accB[co] = acc2[co].y; }
    conv_epilogue(accA, b, r,     p,     confidence, feat_fix, out_off, out_aff, packed);
    conv_epilogue(accB, b, r + 1, p + 1, confidence, feat_fix, out_off, out_aff, packed);
}

// ---------------------------------------------------------------------------
// Kernel B (packed): one propagation step; paired-corner float2 gathers.
// ---------------------------------------------------------------------------
__global__ __launch_bounds__(256) void prop_packed_kernel(
    const float* __restrict__ src,   // [B,H,W] prev frame
    float* __restrict__ dst,         // [B,H,W] this iter's list slot
    const uint4* __restrict__ packed,
    const float* __restrict__ w9,    // [9]
    const float* __restrict__ biasp, // [1]
    float* __restrict__ out_pred)    // pred slot or nullptr
{
    int p = blockIdx.x * 256 + threadIdx.x;
    if (p >= NPIX) return;
    int b = p / HW;
    int r = p - b * HW;
    int y = r / WW;
    int x = r - y * WW;

    const uint4* pk = packed + (size_t)p * 4;
    uint4 q0 = pk[0], q1 = pk[1], q2 = pk[2], q3 = pk[3];
    unsigned uu[14] = {q0.x, q0.y, q0.z, q0.w, q1.x, q1.y, q1.z, q1.w,
                       q2.x, q2.y, q2.z, q2.w, q3.x, q3.y};
    float hv[27];
#pragma unroll
    for (int i = 0; i < 13; ++i) {
        hv[2 * i]     = __half2float(__ushort_as_half((unsigned short)(uu[i] & 0xffff)));
        hv[2 * i + 1] = __half2float(__ushort_as_half((unsigned short)(uu[i] >> 16)));
    }
    hv[26] = __half2float(__ushort_as_half((unsigned short)(uu[13] & 0xffff)));
    float cm1 = __uint_as_float(q3.z);
    float cff = __uint_as_float(q3.w);

    const float* sf = src + (size_t)b * HW;
    float acc = 0.f;
#pragma unroll
    for (int k = 0; k < 9; ++k) {
        float py = (float)y + (float)(k / 3 - 1) + hv[2 * k];
        float px = (float)x + (float)(k % 3 - 1) + hv[2 * k + 1];
        float y0f = floorf(py), x0f = floorf(px);
        float ty = py - y0f, tx = px - x0f;
        int iy = (int)y0f, ix = (int)x0f;
        int idx = iy * WW + ix;
        bool vy0 = ((unsigned)iy < HH), vy1 = ((unsigned)(iy + 1) < HH);
        bool fastx = ((unsigned)ix < (WW - 1));
        float v00, v01, v10, v11;
        if (vy0) {
            if (fastx) { float2 t2 = ld2(sf + idx); v00 = t2.x; v01 = t2.y; }
            else {
                v00 = ((unsigned)ix < WW) ? sf[idx] : 0.f;
                v01 = ((unsigned)(ix + 1) < WW) ? sf[idx + 1] : 0.f;
            }
        } else { v00 = 0.f; v01 = 0.f; }
        if (vy1) {
            if (fastx) { float2 t2 = ld2(sf + idx + WW); v10 = t2.x; v11 = t2.y; }
            else {
                v10 = ((unsigned)ix < WW) ? sf[idx + WW] : 0.f;
                v11 = ((unsigned)(ix + 1) < WW) ? sf[idx + WW + 1] : 0.f;
            }
        } else { v10 = 0.f; v11 = 0.f; }
        float top = (1.f - tx) * v00 + tx * v01;
        float bot = (1.f - tx) * v10 + tx * v11;
        float sv = (1.f - ty) * top + ty * bot;
        acc = fmaf(sv * hv[18 + k], w9[k], acc);
    }
    float dc = acc + biasp[0];
    float fr = fmaf(cm1, dc, cff);

    dst[p] = fr;
    if (out_pred) out_pred[p] = fr;
}

// ---------------------------------------------------------------------------
// Kernel B (fallback, no ws): reads f32 off/aff planes from the output buf.
// ---------------------------------------------------------------------------
__global__ __launch_bounds__(256) void prop_kernel(
    const float* __restrict__ src,
    float* __restrict__ dst,
    const float* __restrict__ off,
    const float* __restrict__ aff,
    const float* __restrict__ confidence,
    const float* __restrict__ feat_fix,
    const float* __restrict__ w9,
    const float* __restrict__ biasp,
    float* __restrict__ out_pred)
{
    int p = blockIdx.x * 256 + threadIdx.x;
    if (p >= NPIX) return;
    int b = p / HW;
    int r = p - b * HW;
    int y = r / WW;
    int x = r - y * WW;

    const float* offb = off + (size_t)b * 18 * HW + r;
    const float* affb = aff + (size_t)b * 9 * HW + r;
    const float* sf = src + (size_t)b * HW;

    float acc = 0.f;
#pragma unroll
    for (int k = 0; k < 9; ++k) {
        float dy = offb[(size_t)(2 * k) * HW];
        float dx = offb[(size_t)(2 * k + 1) * HW];
        float af = affb[(size_t)k * HW];
        float py = (float)y + (float)(k / 3 - 1) + dy;
        float px = (float)x + (float)(k % 3 - 1) + dx;
        float y0f = floorf(py), x0f = floorf(px);
        float ty = py - y0f, tx = px - x0f;
        int iy = (int)y0f, ix = (int)x0f;
        bool vy0 = ((unsigned)iy < HH), vy1 = ((unsigned)(iy + 1) < HH);
        bool vx0 = ((unsigned)ix < WW), vx1 = ((unsigned)(ix + 1) < WW);
        float v00 = (vy0 && vx0) ? sf[(size_t)iy * WW + ix] : 0.f;
        float v01 = (vy0 && vx1) ? sf[(size_t)iy * WW + ix + 1] : 0.f;
        float v10 = (vy1 && vx0) ? sf[(size_t)(iy + 1) * WW + ix] : 0.f;
        float v11 = (vy1 && vx1) ? sf[(size_t)(iy + 1) * WW + ix + 1] : 0.f;
        float top = (1.f - tx) * v00 + tx * v01;
        float bot = (1.f - tx) * v10 + tx * v11;
        float sv = (1.f - ty) * top + ty * bot;
        acc = fmaf(sv * af, w9[k], acc);
    }
    float dc = acc + biasp[0];

    float cf = confidence[p];
    float ffv = feat_fix[p];
    float sg = (ffv > 0.f) ? 1.f : ((ffv < 0.f) ? -1.f : 0.f);
    float conf = sg / (1.f + expf(-cf));
    float fr = (1.f - conf) * dc + conf * ffv;

    dst[p] = fr;
    if (out_pred) out_pred[p] = fr;
}

// ---------------------------------------------------------------------------
extern "C" void kernel_launch(void* const* d_in, const int* in_sizes, int n_in,
                              void* d_out, int out_size, void* d_ws, size_t ws_size,
                              hipStream_t stream) {
    const float* feat_init  = (const float*)d_in[0];
    const float* guidance   = (const float*)d_in[1];
    const float* confidence = (const float*)d_in[2];
    const float* feat_fix   = (const float*)d_in[3];
    const float* conv_w     = (const float*)d_in[4];
    const float* conv_b     = (const float*)d_in[5];
    const float* w          = (const float*)d_in[6];
    const float* bias       = (const float*)d_in[7];

    float* outf = (float*)d_out;
    float* out_pred = outf;                         // [B,1,H,W]
    float* out_list = outf + (size_t)NPIX;          // [18,B,1,H,W]
    float* out_off  = outf + (size_t)19 * NPIX;     // [B,18,H,W]
    float* out_aff  = outf + (size_t)37 * NPIX;     // [B,9,H,W]

    bool use_pack = (ws_size >= PACK_BYTES);
    uint4* packed = use_pack ? (uint4*)d_ws : nullptr;

    int cblocks = (NPIX / 2 + 255) / 256;
    conv_pack_kernel<<<cblocks, 256, 0, stream>>>(
        guidance, conv_w, conv_b, confidence, feat_fix,
        out_off, out_aff, packed);

    int blocks = (NPIX + 255) / 256;
    const float* src = feat_init;
    for (int it = 0; it < NITER; ++it) {
        float* dstf = out_list + (size_t)it * NPIX;
        float* predp = (it == NITER - 1) ? out_pred : nullptr;
        if (use_pack) {
            prop_packed_kernel<<<blocks, 256, 0, stream>>>(
                src, dstf, packed, w, bias, predp);
        } else {
            prop_kernel<<<blocks, 256, 0, stream>>>(
                src, dstf, out_off, out_aff, confidence, feat_fix, w, bias, predp);
        }
        src = dstf;
    }
}

// Round 6
// 511.252 us; speedup vs baseline: 1.1932x; 1.1932x over previous
//
#include <hip/hip_runtime.h>
#include <hip/hip_fp16.h>

#define HH 352
#define WW 1216
#define HW (HH*WW)
#define NPIX (2*HW)      // 856064
#define NITER 18
#define PACK_BYTES ((size_t)NPIX * 64)

// prop LDS tile geometry
#define SEG 256
#define XHALO 6
#define YHALO 4
#define TROWS 10                 // YHALO + 1 + 5 (rows y-4 .. y+5)
#define TCOLS (SEG + 2*XHALO)    // 268
#define NSEG ((WW + SEG - 1) / SEG)   // 5

// ---------------------------------------------------------------------------
// 9 taps of one input channel -> 27 output-channel accumulators.
// cw indexed wave-uniformly -> compiler scalarizes weights into SGPRs.
// ---------------------------------------------------------------------------
__device__ __forceinline__ void fma_9x27(const float v[9],
                                         const float* __restrict__ cw,
                                         int ci, float acc[27]) {
#pragma unroll
    for (int t = 0; t < 9; ++t)
#pragma unroll
        for (int co = 0; co < 27; ++co)
            acc[co] = fmaf(v[t], cw[co * 81 + ci * 9 + t], acc[co]);
}

// ---------------------------------------------------------------------------
// Kernel A: 3x3 conv (9->27ch, pad 1) + fp16 quantize + softmax (round-4 ver).
// ---------------------------------------------------------------------------
__global__ __launch_bounds__(256) void conv_pack_kernel(
    const float* __restrict__ g,          // [B,9,H,W]
    const float* __restrict__ cw,         // [27,9,3,3]
    const float* __restrict__ cb,         // [27]
    const float* __restrict__ confidence, // [B,1,H,W]
    const float* __restrict__ feat_fix,   // [B,1,H,W]
    float* __restrict__ out_off,          // [B,18,H,W]
    float* __restrict__ out_aff,          // [B,9,H,W]
    uint4* __restrict__ packed)           // [NPIX][4] or nullptr
{
    int p = blockIdx.x * 256 + threadIdx.x;
    if (p >= NPIX) return;
    int b = p / HW;
    int r = p - b * HW;
    int y = r / WW;
    int x = r - y * WW;

    float acc[27];
#pragma unroll
    for (int co = 0; co < 27; ++co) acc[co] = cb[co];

    const float* gb = g + (size_t)b * 9 * HW;
    bool interior = (y >= 1) & (y <= HH - 2) & (x >= 1) & (x <= WW - 2);
    if (interior) {
        const float* c0 = gb + (size_t)(y - 1) * WW + (x - 1);
        for (int ci = 0; ci < 9; ++ci) {
            const float* cp = c0 + (size_t)ci * HW;
            float v[9];
            v[0] = cp[0];          v[1] = cp[1];          v[2] = cp[2];
            v[3] = cp[WW];         v[4] = cp[WW + 1];     v[5] = cp[WW + 2];
            v[6] = cp[2 * WW];     v[7] = cp[2 * WW + 1]; v[8] = cp[2 * WW + 2];
            fma_9x27(v, cw, ci, acc);
        }
    } else {
        for (int ci = 0; ci < 9; ++ci) {
            const float* cp = gb + (size_t)ci * HW;
            float v[9];
#pragma unroll
            for (int t = 0; t < 9; ++t) {
                int yy = y + t / 3 - 1;
                int xx = x + t % 3 - 1;
                v[t] = ((unsigned)yy < HH && (unsigned)xx < WW)
                           ? cp[(size_t)yy * WW + xx] : 0.f;
            }
            fma_9x27(v, cw, ci, acc);
        }
    }

    // fp16 RNE quantization (reference .half() then .float())
    __half h[28];
#pragma unroll
    for (int c = 0; c < 18; ++c) h[c] = __float2half(acc[c]);

    float m = acc[18];
#pragma unroll
    for (int c = 19; c < 27; ++c) m = fmaxf(m, acc[c]);
    float e[9], s = 0.f;
#pragma unroll
    for (int k = 0; k < 9; ++k) { e[k] = expf(acc[18 + k] - m); s += e[k]; }
    float inv = 1.f / s;
#pragma unroll
    for (int k = 0; k < 9; ++k) h[18 + k] = __float2half(e[k] * inv);
    h[27] = __float2half(0.f);

    // required f32 outputs
#pragma unroll
    for (int c = 0; c < 18; ++c)
        out_off[(size_t)b * 18 * HW + (size_t)c * HW + r] = __half2float(h[c]);
#pragma unroll
    for (int k = 0; k < 9; ++k)
        out_aff[(size_t)b * 9 * HW + (size_t)k * HW + r] = __half2float(h[18 + k]);

    if (packed) {
        float cf = confidence[p];
        float ff = feat_fix[p];
        float sg = (ff > 0.f) ? 1.f : ((ff < 0.f) ? -1.f : 0.f);
        float conf = sg / (1.f + expf(-cf));

        unsigned uu[16];
#pragma unroll
        for (int i = 0; i < 14; ++i)
            uu[i] = (unsigned)__half_as_ushort(h[2 * i]) |
                    ((unsigned)__half_as_ushort(h[2 * i + 1]) << 16);
        uu[14] = __float_as_uint(1.f - conf);   // cm1
        uu[15] = __float_as_uint(conf * ff);    // cff

        uint4* dst = packed + (size_t)p * 4;
        dst[0] = make_uint4(uu[0], uu[1], uu[2], uu[3]);
        dst[1] = make_uint4(uu[4], uu[5], uu[6], uu[7]);
        dst[2] = make_uint4(uu[8], uu[9], uu[10], uu[11]);
        dst[3] = make_uint4(uu[12], uu[13], uu[14], uu[15]);
    }
}

// ---------------------------------------------------------------------------
// Kernel B (packed + LDS tile): one propagation step.
// Block = 256 threads = one row-segment (b, y, xs..xs+255).
// Stage rows y-4..y+5, cols xs-6..xs+261 (zero outside image) into LDS;
// bilinear corners come from LDS (conflict-free: lane addr ~ tid + const).
// Rare out-of-tile samples fall back to guarded global loads.
// ---------------------------------------------------------------------------
__global__ __launch_bounds__(256) void prop_lds_kernel(
    const float* __restrict__ src,   // [B,H,W] prev frame
    float* __restrict__ dst,         // [B,H,W] this iter's list slot
    const uint4* __restrict__ packed,
    const float* __restrict__ w9,    // [9]
    const float* __restrict__ biasp, // [1]
    float* __restrict__ out_pred)    // pred slot or nullptr
{
    __shared__ float tile[TROWS * TCOLS];

    const int xs = blockIdx.x * SEG;
    const int y  = blockIdx.y;
    const int b  = blockIdx.z;
    const float* sf = src + (size_t)b * HW;

    // cooperative zero-padded staging
    for (int i = threadIdx.x; i < TROWS * TCOLS; i += 256) {
        int rr = i / TCOLS;
        int cc = i - rr * TCOLS;
        int gy = y - YHALO + rr;
        int gx = xs - XHALO + cc;
        float v = 0.f;
        if ((unsigned)gy < HH && (unsigned)gx < WW)
            v = sf[(size_t)gy * WW + gx];
        tile[i] = v;
    }
    __syncthreads();

    int x = xs + threadIdx.x;
    if (x >= WW) return;
    int r = y * WW + x;
    int p = b * HW + r;

    const uint4* pk = packed + (size_t)p * 4;
    uint4 q0 = pk[0], q1 = pk[1], q2 = pk[2], q3 = pk[3];
    unsigned uu[14] = {q0.x, q0.y, q0.z, q0.w, q1.x, q1.y, q1.z, q1.w,
                       q2.x, q2.y, q2.z, q2.w, q3.x, q3.y};
    float hv[27];
#pragma unroll
    for (int i = 0; i < 13; ++i) {
        hv[2 * i]     = __half2float(__ushort_as_half((unsigned short)(uu[i] & 0xffff)));
        hv[2 * i + 1] = __half2float(__ushort_as_half((unsigned short)(uu[i] >> 16)));
    }
    hv[26] = __half2float(__ushort_as_half((unsigned short)(uu[13] & 0xffff)));
    float cm1 = __uint_as_float(q3.z);
    float cff = __uint_as_float(q3.w);

    float acc = 0.f;
#pragma unroll
    for (int k = 0; k < 9; ++k) {
        float py = (float)y + (float)(k / 3 - 1) + hv[2 * k];
        float px = (float)x + (float)(k % 3 - 1) + hv[2 * k + 1];
        float y0f = floorf(py), x0f = floorf(px);
        float ty = py - y0f, tx = px - x0f;
        int iy = (int)y0f, ix = (int)x0f;

        int ly = iy - y + YHALO;       // tile row of top corner
        int lx = ix - xs + XHALO;      // tile col of left corner
        float v00, v01, v10, v11;
        if ((unsigned)ly < (TROWS - 1) && (unsigned)lx < (TCOLS - 1)) {
            const float* t0 = &tile[ly * TCOLS + lx];
            v00 = t0[0];     v01 = t0[1];
            v10 = t0[TCOLS]; v11 = t0[TCOLS + 1];
        } else {
            bool vy0 = ((unsigned)iy < HH), vy1 = ((unsigned)(iy + 1) < HH);
            bool vx0 = ((unsigned)ix < WW), vx1 = ((unsigned)(ix + 1) < WW);
            v00 = (vy0 && vx0) ? sf[(size_t)iy * WW + ix] : 0.f;
            v01 = (vy0 && vx1) ? sf[(size_t)iy * WW + ix + 1] : 0.f;
            v10 = (vy1 && vx0) ? sf[(size_t)(iy + 1) * WW + ix] : 0.f;
            v11 = (vy1 && vx1) ? sf[(size_t)(iy + 1) * WW + ix + 1] : 0.f;
        }
        float top = (1.f - tx) * v00 + tx * v01;
        float bot = (1.f - tx) * v10 + tx * v11;
        float sv = (1.f - ty) * top + ty * bot;
        acc = fmaf(sv * hv[18 + k], w9[k], acc);
    }
    float dc = acc + biasp[0];
    float fr = fmaf(cm1, dc, cff);

    dst[p] = fr;
    if (out_pred) out_pred[p] = fr;
}

// ---------------------------------------------------------------------------
// Kernel B (fallback, no ws): reads f32 off/aff planes from the output buf.
// ---------------------------------------------------------------------------
__global__ __launch_bounds__(256) void prop_kernel(
    const float* __restrict__ src,
    float* __restrict__ dst,
    const float* __restrict__ off,
    const float* __restrict__ aff,
    const float* __restrict__ confidence,
    const float* __restrict__ feat_fix,
    const float* __restrict__ w9,
    const float* __restrict__ biasp,
    float* __restrict__ out_pred)
{
    int p = blockIdx.x * 256 + threadIdx.x;
    if (p >= NPIX) return;
    int b = p / HW;
    int r = p - b * HW;
    int y = r / WW;
    int x = r - y * WW;

    const float* offb = off + (size_t)b * 18 * HW + r;
    const float* affb = aff + (size_t)b * 9 * HW + r;
    const float* sf = src + (size_t)b * HW;

    float acc = 0.f;
#pragma unroll
    for (int k = 0; k < 9; ++k) {
        float dy = offb[(size_t)(2 * k) * HW];
        float dx = offb[(size_t)(2 * k + 1) * HW];
        float af = affb[(size_t)k * HW];
        float py = (float)y + (float)(k / 3 - 1) + dy;
        float px = (float)x + (float)(k % 3 - 1) + dx;
        float y0f = floorf(py), x0f = floorf(px);
        float ty = py - y0f, tx = px - x0f;
        int iy = (int)y0f, ix = (int)x0f;
        bool vy0 = ((unsigned)iy < HH), vy1 = ((unsigned)(iy + 1) < HH);
        bool vx0 = ((unsigned)ix < WW), vx1 = ((unsigned)(ix + 1) < WW);
        float v00 = (vy0 && vx0) ? sf[(size_t)iy * WW + ix] : 0.f;
        float v01 = (vy0 && vx1) ? sf[(size_t)iy * WW + ix + 1] : 0.f;
        float v10 = (vy1 && vx0) ? sf[(size_t)(iy + 1) * WW + ix] : 0.f;
        float v11 = (vy1 && vx1) ? sf[(size_t)(iy + 1) * WW + ix + 1] : 0.f;
        float top = (1.f - tx) * v00 + tx * v01;
        float bot = (1.f - tx) * v10 + tx * v11;
        float sv = (1.f - ty) * top + ty * bot;
        acc = fmaf(sv * af, w9[k], acc);
    }
    float dc = acc + biasp[0];

    float cf = confidence[p];
    float ffv = feat_fix[p];
    float sg = (ffv > 0.f) ? 1.f : ((ffv < 0.f) ? -1.f : 0.f);
    float conf = sg / (1.f + expf(-cf));
    float fr = (1.f - conf) * dc + conf * ffv;

    dst[p] = fr;
    if (out_pred) out_pred[p] = fr;
}

// ---------------------------------------------------------------------------
extern "C" void kernel_launch(void* const* d_in, const int* in_sizes, int n_in,
                              void* d_out, int out_size, void* d_ws, size_t ws_size,
                              hipStream_t stream) {
    const float* feat_init  = (const float*)d_in[0];
    const float* guidance   = (const float*)d_in[1];
    const float* confidence = (const float*)d_in[2];
    const float* feat_fix   = (const float*)d_in[3];
    const float* conv_w     = (const float*)d_in[4];
    const float* conv_b     = (const float*)d_in[5];
    const float* w          = (const float*)d_in[6];
    const float* bias       = (const float*)d_in[7];

    float* outf = (float*)d_out;
    float* out_pred = outf;                         // [B,1,H,W]
    float* out_list = outf + (size_t)NPIX;          // [18,B,1,H,W]
    float* out_off  = outf + (size_t)19 * NPIX;     // [B,18,H,W]
    float* out_aff  = outf + (size_t)37 * NPIX;     // [B,9,H,W]

    bool use_pack = (ws_size >= PACK_BYTES);
    uint4* packed = use_pack ? (uint4*)d_ws : nullptr;

    int blocks = (NPIX + 255) / 256;
    conv_pack_kernel<<<blocks, 256, 0, stream>>>(
        guidance, conv_w, conv_b, confidence, feat_fix,
        out_off, out_aff, packed);

    dim3 pgrid(NSEG, HH, 2);
    const float* src = feat_init;
    for (int it = 0; it < NITER; ++it) {
        float* dstf = out_list + (size_t)it * NPIX;
        float* predp = (it == NITER - 1) ? out_pred : nullptr;
        if (use_pack) {
            prop_lds_kernel<<<pgrid, 256, 0, stream>>>(
                src, dstf, packed, w, bias, predp);
        } else {
            prop_kernel<<<blocks, 256, 0, stream>>>(
                src, dstf, out_off, out_aff, confidence, feat_fix, w, bias, predp);
        }
        src = dstf;
    }
}